// Round 1
// baseline (230.605 us; speedup 1.0000x reference)
//
#include <hip/hip_runtime.h>
#include <math.h>

// Problem constants (reference: K=256, Q=64, T=500001 -> n = 500000)
#define K_ 256
#define Q_ 64
#define NT 500000
#define NTILES (NT / 16)      // 31250 t-tiles of 16
#define TT_ 16                // t-tiles per block
#define NBLK ((NT + 255) / 256)               // 1954 u2 blocks
#define GRID_MAIN ((NTILES + TT_ - 1) / TT_)  // 1954 k_main blocks
#define PREP_THREADS (16384 + 2 * K_)         // 16896
#define PREP_BLOCKS ((PREP_THREADS + 255) / 256)  // 66

// Workspace layout (float offsets):
//  [0]                   finish counter (unsigned; zeroed by k_front)
//  [2]                   softplus(raw_beta0)
//  [WS_U2B0 .. )         bf16 u2_full            (ushort, len Q_+NT)
//  [WS_U2B1 .. )         bf16 u2_full shifted+1  (ushort, len Q_+NT; [e]=u2f[e+1])
//  [WS_BPACK .. )        W in MFMA fragment order (ushort, 16*2*64*8 = 16384)
//  [WS_W0 .. +K_)        softplus(raw_w0) fp32
//  [WS_BETA .. +K_)      softplus(raw_beta) fp32
//  [WS_PART/2 .. +2048)  per-block sum(u2), sum(u2^2) partials
//  [WS_OUT .. +2048)     per-block NLL partials (summed by last k_main block)
#define WS_CNT    0
#define WS_BETA0  2
#define WS_U2B0   4
#define WS_U2B1   (WS_U2B0 + (Q_ + NT + 1) / 2)
#define WS_BPACK  (WS_U2B1 + (Q_ + NT + 1) / 2)
#define WS_W0     (WS_BPACK + 8192)
#define WS_BETA   (WS_W0 + K_)
#define WS_PART   (WS_BETA + K_)
#define WS_PART2  (WS_PART + 2048)
#define WS_OUT    (WS_PART2 + 2048)

typedef __attribute__((ext_vector_type(8))) __bf16 bf16x8;
typedef __attribute__((ext_vector_type(4))) float  f32x4;

__device__ __forceinline__ float softplusf(float x) {
    return (x > 20.f) ? x : log1pf(__expf(x));
}

__device__ __forceinline__ unsigned short f2bf(float f) {
    unsigned int u = __float_as_uint(f);
    u = u + 0x7FFFu + ((u >> 16) & 1u);   // RNE (positive normals here)
    return (unsigned short)(u >> 16);
}

// Kernel A (merged u2 + prep): blocks [0,NBLK) compute u2 -> two bf16 copies
// + per-block sum(u2)/sum(u2^2) partials. Blocks [NBLK, NBLK+PREP_BLOCKS)
// pack W fragments, softplus w0/beta/beta0, and zero the finish counter.
// (W-pack has no dependency on u2, so it rides in the same dispatch; the
// var-init, which DOES need all u2 partials, moved to k_main block 0.)
__global__ void k_front(const float* __restrict__ r,
                        const float* __restrict__ a0p,
                        const float* __restrict__ a1p,
                        const float* __restrict__ raw_beta0,
                        const float* __restrict__ raw_beta,
                        const float* __restrict__ raw_w0,
                        const float* __restrict__ raw_w,
                        float* __restrict__ ws) {
    __shared__ float red[8];
    int bi = blockIdx.x - NBLK;
    if (bi < 0) {
        int i = blockIdx.x * blockDim.x + threadIdx.x;
        float a0 = a0p[0], a1 = a1p[0];
        float v = 0.f, v2 = 0.f;
        if (i < NT) {
            float u  = r[i + 1] - a0 - a1 * r[i];
            float u2 = u * u;
            unsigned short b = f2bf(u2);
            ((unsigned short*)(ws + WS_U2B0))[Q_ + i]     = b;
            ((unsigned short*)(ws + WS_U2B1))[Q_ + i - 1] = b;   // [e] = u2f[e+1]
            v = u2; v2 = u2 * u2;
        }
        #pragma unroll
        for (int off = 32; off > 0; off >>= 1) {
            v  += __shfl_down(v,  off, 64);
            v2 += __shfl_down(v2, off, 64);
        }
        int wv = threadIdx.x >> 6;
        if ((threadIdx.x & 63) == 0) { red[wv * 2] = v; red[wv * 2 + 1] = v2; }
        __syncthreads();
        if (threadIdx.x == 0) {
            ws[WS_PART  + blockIdx.x] = red[0] + red[2] + red[4] + red[6];
            ws[WS_PART2 + blockIdx.x] = red[1] + red[3] + red[5] + red[7];
        }
    } else {
        int idx = bi * 256 + threadIdx.x;
        if (idx < 16384) {
            // Wpack[((kc*2+s)*64 + l)*8 + jj] = W'[32s + 8*(l>>4) + jj][kc*16 + (l&15)]
            // where W'[j][kout] = softplus(raw_w[kout][63-j]).
            int jj = idx & 7, l = (idx >> 3) & 63, s = (idx >> 9) & 1, kc = idx >> 10;
            int j    = 32 * s + 8 * (l >> 4) + jj;
            int kout = kc * 16 + (l & 15);
            ((unsigned short*)(ws + WS_BPACK))[idx] =
                f2bf(softplusf(raw_w[kout * Q_ + (Q_ - 1 - j)]));
        } else if (idx < 16384 + K_) {
            int k = idx - 16384;
            ws[WS_W0 + k] = softplusf(raw_w0[k]);
            if (k == 0) {
                ws[WS_BETA0] = softplusf(raw_beta0[0]);
                ((unsigned int*)ws)[WS_CNT] = 0u;   // finish counter (ws is poisoned)
            }
        } else if (idx < 16384 + 2 * K_) {
            int k = idx - (16384 + K_);
            ws[WS_BETA + k] = softplusf(raw_beta[k]);
        }
    }
}

// Kernel B: bf16 MFMA sliding-window GEMM + fused NLL partial + finalize.
// W is the A-operand, u2 window the B-operand, so C/D rows (quad*4+reg)=kout,
// cols (lane&15)=t; the k-reduction is within-lane — no in-loop cross-lane ops.
// Block 0 prologue computes the var(u2) init entries (only block 0 ever reads
// u2_full[0..63]). Last-finishing block (fence + atomic ticket) sums the
// per-block NLL partials and writes out[0] — replaces the k_final dispatch.
__launch_bounds__(256, 4)
__global__ void k_main(const float* __restrict__ r,
                       const float* __restrict__ a0p,
                       const float* __restrict__ a1p,
                       float* __restrict__ ws,
                       float* __restrict__ out) {
    __shared__ __align__(16) float sig[TT_ * 272];   // stride 272: 2-way (free) banks in epilogue
    __shared__ float red[4];
    __shared__ int amLast;

    int tid = threadIdx.x;
    int l = tid & 63, w = tid >> 6;
    int m = l & 15, q = l >> 4;

    // Block 0: var-init entries of u2_full (depends on k_front partials).
    // Must complete before block 0's own B-fragment prefetch below.
    if (blockIdx.x == 0) {
        if (tid < 64) {
            float s1 = 0.f, s2 = 0.f;
            for (int p = tid; p < NBLK; p += 64) {
                s1 += ws[WS_PART  + p];
                s2 += ws[WS_PART2 + p];
            }
            #pragma unroll
            for (int mask = 1; mask < 64; mask <<= 1) {
                s1 += __shfl_xor(s1, mask, 64);
                s2 += __shfl_xor(s2, mask, 64);
            }
            float n   = (float)NT;
            float var = (s2 - s1 * s1 / n) / (n - 1.f);
            unsigned short b = f2bf(var);
            ((unsigned short*)(ws + WS_U2B0))[tid] = b;
            if (tid < Q_ - 1) ((unsigned short*)(ws + WS_U2B1))[tid] = b;
        }
        __syncthreads();   // global writes visible block-wide (same CU/L1)
    }

    const unsigned short* bp = (const unsigned short*)(ws + WS_BPACK);
    float beta0v = ws[WS_BETA0];
    float a0 = a0p[0], a1 = a1p[0];

    // Preload W fragments (A-operand) and per-lane w0/beta float4s
    // (kout = kc*16 + q*4 + rr  ->  q-dependent vector loads, 16B aligned).
    bf16x8 Wf[4][2];
    f32x4 w0c[4], betc[4];
    #pragma unroll
    for (int i = 0; i < 4; ++i) {
        int kc = w * 4 + i;
        #pragma unroll
        for (int s = 0; s < 2; ++s)
            __builtin_memcpy(&Wf[i][s], bp + ((kc * 2 + s) * 64 + l) * 8, 16);
        w0c[i]  = *(const f32x4*)(ws + WS_W0   + kc * 16 + q * 4);
        betc[i] = *(const f32x4*)(ws + WS_BETA + kc * 16 + q * 4);
    }

    // u2 B-fragment: lane needs u2full[s0..s0+7], s0 = t0 + m + 8q (+32).
    // parity(s0)=m&1: even -> u2b0[s0], odd -> u2b1[s0-1] (4B-aligned loads).
    int par = m & 1;
    const char* abase = (const char*)(ws + (par ? WS_U2B1 : WS_U2B0));
    int tile0 = blockIdx.x * TT_;
    int aoff = (tile0 * 16 + m + 8 * q - par) * 2;   // bytes

    bf16x8 U0, U1, U0n, U1n;
    __builtin_memcpy(&U0, abase + aoff, 16);
    __builtin_memcpy(&U1, abase + aoff + 64, 16);

    // Last block: reads past the valid range stay inside ws (garbage masked
    // in the epilogue), including the one-tile prefetch overshoot.
    #pragma unroll 2
    for (int it = 0; it < TT_; ++it) {
        int anext = aoff + 32;
        __builtin_memcpy(&U0n, abase + anext, 16);
        __builtin_memcpy(&U1n, abase + anext + 64, 16);

        float p[4];
        #pragma unroll
        for (int i = 0; i < 4; ++i) {
            f32x4 acc = __builtin_amdgcn_mfma_f32_16x16x32_bf16(Wf[i][0], U0, w0c[i], 0, 0, 0);
            acc = __builtin_amdgcn_mfma_f32_16x16x32_bf16(Wf[i][1], U1, acc, 0, 0, 0);
            float pi;
            pi = betc[i][0] * fmaxf(acc[0], 0.f);
            pi = fmaf(betc[i][1], fmaxf(acc[1], 0.f), pi);
            pi = fmaf(betc[i][2], fmaxf(acc[2], 0.f), pi);
            pi = fmaf(betc[i][3], fmaxf(acc[3], 0.f), pi);
            p[i] = pi;
        }
        sig[it * 272 + tid] = (p[0] + p[1]) + (p[2] + p[3]);

        aoff = anext; U0 = U0n; U1 = U1n;
    }

    __syncthreads();   // the ONLY barrier before epilogue

    // Epilogue: thread tid owns t = tile0*16 + tid; sum its 16 partials.
    int tile = tid >> 4, tt = tid & 15;
    const float* sp = &sig[tile * 272 + tt];
    float s = 0.f;
    #pragma unroll
    for (int wq = 0; wq < 16; ++wq) s += sp[wq * 16];
    float sg = beta0v + s + 1e-8f;
    int t = tile0 * 16 + tid;
    float val = 0.f;
    if (t < NT) {
        float u = r[t + 1] - a0 - a1 * r[t];   // recompute u2 (fp32-identical)
        val = __logf(sg) + u * u / sg;
    }

    #pragma unroll
    for (int mask = 1; mask < 64; mask <<= 1)
        val += __shfl_xor(val, mask, 64);
    if (l == 0) red[w] = val;
    __syncthreads();
    if (tid == 0)
        ws[WS_OUT + blockIdx.x] = red[0] + red[1] + red[2] + red[3];

    // Finalize in the last-finishing block (fence + ticket, CUDA
    // threadFenceReduction pattern; device-scope atomics per G12).
    __threadfence();                       // release WS_OUT partial
    if (tid == 0) {
        unsigned c = atomicAdd((unsigned int*)ws + WS_CNT, 1u);
        amLast = (c == GRID_MAIN - 1);
    }
    __syncthreads();
    if (amLast) {
        __threadfence();                   // acquire: L1 inv before reading partials
        float fs = 0.f;
        for (int p = tid; p < GRID_MAIN; p += 256) fs += ws[WS_OUT + p];
        #pragma unroll
        for (int mask = 1; mask < 64; mask <<= 1)
            fs += __shfl_xor(fs, mask, 64);
        if (l == 0) red[w] = fs;
        __syncthreads();
        if (tid == 0)
            out[0] = 0.5f * (float)NT * 1.8378770664093453f
                   + 0.5f * (red[0] + red[1] + red[2] + red[3]);
    }
}

extern "C" void kernel_launch(void* const* d_in, const int* in_sizes, int n_in,
                              void* d_out, int out_size, void* d_ws, size_t ws_size,
                              hipStream_t stream) {
    const float* r        = (const float*)d_in[0];
    const float* a0       = (const float*)d_in[1];
    const float* a1       = (const float*)d_in[2];
    const float* raw_b0   = (const float*)d_in[3];
    const float* raw_beta = (const float*)d_in[4];
    const float* raw_w0   = (const float*)d_in[5];
    const float* raw_w    = (const float*)d_in[6];
    float* out = (float*)d_out;
    float* ws  = (float*)d_ws;

    k_front<<<NBLK + PREP_BLOCKS, 256, 0, stream>>>(
        r, a0, a1, raw_b0, raw_beta, raw_w0, raw_w, ws);

    k_main<<<GRID_MAIN, 256, 0, stream>>>(r, a0, a1, ws, out);
}

// Round 2
// 91.126 us; speedup vs baseline: 2.5306x; 2.5306x over previous
//
#include <hip/hip_runtime.h>
#include <math.h>

// Problem constants (reference: K=256, Q=64, T=500001 -> n = 500000)
#define K_ 256
#define Q_ 64
#define NT 500000
#define NTILES (NT / 16)      // 31250 t-tiles of 16
#define TT_ 16                // t-tiles per block
#define NBLK ((NT + 255) / 256)               // 1954 u2 blocks
#define GRID_MAIN ((NTILES + TT_ - 1) / TT_)  // 1954 k_main blocks
#define PREP_THREADS (16384 + 2 * K_)         // 16896
#define PREP_BLOCKS ((PREP_THREADS + 255) / 256)  // 66

// Workspace layout (float offsets):
//  [2]                   softplus(raw_beta0)
//  [WS_U2B0 .. )         bf16 u2_full            (ushort, len Q_+NT)
//  [WS_U2B1 .. )         bf16 u2_full shifted+1  (ushort, len Q_+NT; [e]=u2f[e+1])
//  [WS_BPACK .. )        W in MFMA fragment order (ushort, 16*2*64*8 = 16384)
//  [WS_W0 .. +K_)        softplus(raw_w0) fp32
//  [WS_BETA .. +K_)      softplus(raw_beta) fp32
//  [WS_PART/2 .. +2048)  per-block sum(u2), sum(u2^2) partials
//  [WS_OUT .. +2048)     per-block NLL partials (summed by k_final)
#define WS_BETA0  2
#define WS_U2B0   4
#define WS_U2B1   (WS_U2B0 + (Q_ + NT + 1) / 2)
#define WS_BPACK  (WS_U2B1 + (Q_ + NT + 1) / 2)
#define WS_W0     (WS_BPACK + 8192)
#define WS_BETA   (WS_W0 + K_)
#define WS_PART   (WS_BETA + K_)
#define WS_PART2  (WS_PART + 2048)
#define WS_OUT    (WS_PART2 + 2048)

typedef __attribute__((ext_vector_type(8))) __bf16 bf16x8;
typedef __attribute__((ext_vector_type(4))) float  f32x4;

__device__ __forceinline__ float softplusf(float x) {
    return (x > 20.f) ? x : log1pf(__expf(x));
}

__device__ __forceinline__ unsigned short f2bf(float f) {
    unsigned int u = __float_as_uint(f);
    u = u + 0x7FFFu + ((u >> 16) & 1u);   // RNE (positive normals here)
    return (unsigned short)(u >> 16);
}

// Kernel A (merged u2 + prep): blocks [0,NBLK) compute u2 -> two bf16 copies
// + per-block sum(u2)/sum(u2^2) partials. Blocks [NBLK, NBLK+PREP_BLOCKS)
// pack W fragments, softplus w0/beta/beta0.
// (W-pack has no dependency on u2, so it rides in the same dispatch; the
// var-init, which DOES need all u2 partials, lives in k_main block 0.)
__global__ void k_front(const float* __restrict__ r,
                        const float* __restrict__ a0p,
                        const float* __restrict__ a1p,
                        const float* __restrict__ raw_beta0,
                        const float* __restrict__ raw_beta,
                        const float* __restrict__ raw_w0,
                        const float* __restrict__ raw_w,
                        float* __restrict__ ws) {
    __shared__ float red[8];
    int bi = blockIdx.x - NBLK;
    if (bi < 0) {
        int i = blockIdx.x * blockDim.x + threadIdx.x;
        float a0 = a0p[0], a1 = a1p[0];
        float v = 0.f, v2 = 0.f;
        if (i < NT) {
            float u  = r[i + 1] - a0 - a1 * r[i];
            float u2 = u * u;
            unsigned short b = f2bf(u2);
            ((unsigned short*)(ws + WS_U2B0))[Q_ + i]     = b;
            ((unsigned short*)(ws + WS_U2B1))[Q_ + i - 1] = b;   // [e] = u2f[e+1]
            v = u2; v2 = u2 * u2;
        }
        #pragma unroll
        for (int off = 32; off > 0; off >>= 1) {
            v  += __shfl_down(v,  off, 64);
            v2 += __shfl_down(v2, off, 64);
        }
        int wv = threadIdx.x >> 6;
        if ((threadIdx.x & 63) == 0) { red[wv * 2] = v; red[wv * 2 + 1] = v2; }
        __syncthreads();
        if (threadIdx.x == 0) {
            ws[WS_PART  + blockIdx.x] = red[0] + red[2] + red[4] + red[6];
            ws[WS_PART2 + blockIdx.x] = red[1] + red[3] + red[5] + red[7];
        }
    } else {
        int idx = bi * 256 + threadIdx.x;
        if (idx < 16384) {
            // Wpack[((kc*2+s)*64 + l)*8 + jj] = W'[32s + 8*(l>>4) + jj][kc*16 + (l&15)]
            // where W'[j][kout] = softplus(raw_w[kout][63-j]).
            int jj = idx & 7, l = (idx >> 3) & 63, s = (idx >> 9) & 1, kc = idx >> 10;
            int j    = 32 * s + 8 * (l >> 4) + jj;
            int kout = kc * 16 + (l & 15);
            ((unsigned short*)(ws + WS_BPACK))[idx] =
                f2bf(softplusf(raw_w[kout * Q_ + (Q_ - 1 - j)]));
        } else if (idx < 16384 + K_) {
            int k = idx - 16384;
            ws[WS_W0 + k] = softplusf(raw_w0[k]);
            if (k == 0) ws[WS_BETA0] = softplusf(raw_beta0[0]);
        } else if (idx < 16384 + 2 * K_) {
            int k = idx - (16384 + K_);
            ws[WS_BETA + k] = softplusf(raw_beta[k]);
        }
    }
}

// Kernel B: bf16 MFMA sliding-window GEMM + fused NLL partial.
// W is the A-operand, u2 window the B-operand, so C/D rows (quad*4+reg)=kout,
// cols (lane&15)=t; the k-reduction is within-lane — no in-loop cross-lane ops.
// Block 0 prologue computes the var(u2) init entries (only block 0 ever reads
// u2_full[0..63]). Per-block NLL partial -> plain store; k_final sums.
// NOTE R1 post-mortem: do NOT finalize in-kernel. __threadfence() on gfx950
// is an agent-scope fence on a multi-XCD part -> L2 writeback/invalidate per
// block; 1954 blocks of that stalled every pipe (k_main 9us -> 175us).
__launch_bounds__(256, 4)
__global__ void k_main(const float* __restrict__ r,
                       const float* __restrict__ a0p,
                       const float* __restrict__ a1p,
                       float* __restrict__ ws) {
    __shared__ __align__(16) float sig[TT_ * 272];   // stride 272: free 2-way banks in epilogue
    __shared__ float red[4];

    int tid = threadIdx.x;
    int l = tid & 63, w = tid >> 6;
    int m = l & 15, q = l >> 4;

    // Block 0: var-init entries of u2_full (depends on k_front partials).
    // Same-CU L1 makes the writes visible block-wide after __syncthreads().
    if (blockIdx.x == 0) {
        if (tid < 64) {
            float s1 = 0.f, s2 = 0.f;
            for (int p = tid; p < NBLK; p += 64) {
                s1 += ws[WS_PART  + p];
                s2 += ws[WS_PART2 + p];
            }
            #pragma unroll
            for (int mask = 1; mask < 64; mask <<= 1) {
                s1 += __shfl_xor(s1, mask, 64);
                s2 += __shfl_xor(s2, mask, 64);
            }
            float n   = (float)NT;
            float var = (s2 - s1 * s1 / n) / (n - 1.f);
            unsigned short b = f2bf(var);
            ((unsigned short*)(ws + WS_U2B0))[tid] = b;
            if (tid < Q_ - 1) ((unsigned short*)(ws + WS_U2B1))[tid] = b;
        }
        __syncthreads();
    }

    const unsigned short* bp = (const unsigned short*)(ws + WS_BPACK);
    float beta0v = ws[WS_BETA0];
    float a0 = a0p[0], a1 = a1p[0];

    // Preload W fragments (A-operand) and per-lane w0/beta float4s
    // (kout = kc*16 + q*4 + rr  ->  q-dependent vector loads, 16B aligned).
    bf16x8 Wf[4][2];
    f32x4 w0c[4], betc[4];
    #pragma unroll
    for (int i = 0; i < 4; ++i) {
        int kc = w * 4 + i;
        #pragma unroll
        for (int s = 0; s < 2; ++s)
            __builtin_memcpy(&Wf[i][s], bp + ((kc * 2 + s) * 64 + l) * 8, 16);
        w0c[i]  = *(const f32x4*)(ws + WS_W0   + kc * 16 + q * 4);
        betc[i] = *(const f32x4*)(ws + WS_BETA + kc * 16 + q * 4);
    }

    // u2 B-fragment: lane needs u2full[s0..s0+7], s0 = t0 + m + 8q (+32).
    // parity(s0)=m&1: even -> u2b0[s0], odd -> u2b1[s0-1] (4B-aligned loads).
    int par = m & 1;
    const char* abase = (const char*)(ws + (par ? WS_U2B1 : WS_U2B0));
    int tile0 = blockIdx.x * TT_;
    int aoff = (tile0 * 16 + m + 8 * q - par) * 2;   // bytes

    bf16x8 U0, U1, U0n, U1n;
    __builtin_memcpy(&U0, abase + aoff, 16);
    __builtin_memcpy(&U1, abase + aoff + 64, 16);

    // Last block: reads past the valid range stay inside ws (garbage masked
    // in the epilogue), including the one-tile prefetch overshoot.
    #pragma unroll 2
    for (int it = 0; it < TT_; ++it) {
        int anext = aoff + 32;
        __builtin_memcpy(&U0n, abase + anext, 16);
        __builtin_memcpy(&U1n, abase + anext + 64, 16);

        float p[4];
        #pragma unroll
        for (int i = 0; i < 4; ++i) {
            f32x4 acc = __builtin_amdgcn_mfma_f32_16x16x32_bf16(Wf[i][0], U0, w0c[i], 0, 0, 0);
            acc = __builtin_amdgcn_mfma_f32_16x16x32_bf16(Wf[i][1], U1, acc, 0, 0, 0);
            float pi;
            pi = betc[i][0] * fmaxf(acc[0], 0.f);
            pi = fmaf(betc[i][1], fmaxf(acc[1], 0.f), pi);
            pi = fmaf(betc[i][2], fmaxf(acc[2], 0.f), pi);
            pi = fmaf(betc[i][3], fmaxf(acc[3], 0.f), pi);
            p[i] = pi;
        }
        sig[it * 272 + tid] = (p[0] + p[1]) + (p[2] + p[3]);

        aoff = anext; U0 = U0n; U1 = U1n;
    }

    __syncthreads();   // the ONLY barrier before epilogue

    // Epilogue: thread tid owns t = tile0*16 + tid; sum its 16 partials.
    int tile = tid >> 4, tt = tid & 15;
    const float* sp = &sig[tile * 272 + tt];
    float s = 0.f;
    #pragma unroll
    for (int wq = 0; wq < 16; ++wq) s += sp[wq * 16];
    float sg = beta0v + s + 1e-8f;
    int t = tile0 * 16 + tid;
    float val = 0.f;
    if (t < NT) {
        float u = r[t + 1] - a0 - a1 * r[t];   // recompute u2 (fp32-identical)
        val = __logf(sg) + u * u / sg;
    }

    #pragma unroll
    for (int mask = 1; mask < 64; mask <<= 1)
        val += __shfl_xor(val, mask, 64);
    if (l == 0) red[w] = val;
    __syncthreads();
    if (tid == 0)
        ws[WS_OUT + blockIdx.x] = red[0] + red[1] + red[2] + red[3];
}

// Kernel C: sum the per-block NLL partials, add the constant, write out[0].
__global__ void k_final(const float* __restrict__ ws, float* __restrict__ out) {
    __shared__ float red[4];
    int tid = threadIdx.x;
    float s = 0.f;
    for (int p = tid; p < GRID_MAIN; p += 256) s += ws[WS_OUT + p];
    #pragma unroll
    for (int mask = 1; mask < 64; mask <<= 1)
        s += __shfl_xor(s, mask, 64);
    if ((tid & 63) == 0) red[tid >> 6] = s;
    __syncthreads();
    if (tid == 0)
        out[0] = 0.5f * (float)NT * 1.8378770664093453f
               + 0.5f * (red[0] + red[1] + red[2] + red[3]);
}

extern "C" void kernel_launch(void* const* d_in, const int* in_sizes, int n_in,
                              void* d_out, int out_size, void* d_ws, size_t ws_size,
                              hipStream_t stream) {
    const float* r        = (const float*)d_in[0];
    const float* a0       = (const float*)d_in[1];
    const float* a1       = (const float*)d_in[2];
    const float* raw_b0   = (const float*)d_in[3];
    const float* raw_beta = (const float*)d_in[4];
    const float* raw_w0   = (const float*)d_in[5];
    const float* raw_w    = (const float*)d_in[6];
    float* out = (float*)d_out;
    float* ws  = (float*)d_ws;

    k_front<<<NBLK + PREP_BLOCKS, 256, 0, stream>>>(
        r, a0, a1, raw_b0, raw_beta, raw_w0, raw_w, ws);

    k_main<<<GRID_MAIN, 256, 0, stream>>>(r, a0, a1, ws);

    k_final<<<1, 256, 0, stream>>>(ws, out);
}